// Round 6
// baseline (99.831 us; speedup 1.0000x reference)
//
#include <hip/hip_runtime.h>
#include <math.h>

typedef __bf16 bf16x8 __attribute__((ext_vector_type(8)));
typedef float  f32x4  __attribute__((ext_vector_type(4)));

#define B_    4
#define CIN   256
#define COUT  256
#define KK_   9
#define SD    512
#define H_    64
#define W_    64
#define HW    4096
#define KTOT  2304   // KK_*CIN ; k = kk*CIN + c
#define SCALE_     0.0208333333333333332f   // 1/sqrt(256*9)
#define MOD_SCALE_ 0.04419417382415922f     // 1/sqrt(512)
#define SQRT2_     1.4142135623730951f

__device__ __forceinline__ unsigned short f2bf(float f) {
    union { float f; unsigned int u; } v; v.f = f;
    unsigned int r = v.u + 0x7FFFu + ((v.u >> 16) & 1u);   // RNE
    return (unsigned short)(r >> 16);
}

__device__ __forceinline__ void gload_lds16(const void* g, void* l) {
    __builtin_amdgcn_global_load_lds(
        (const __attribute__((address_space(1))) unsigned int*)g,
        (__attribute__((address_space(3))) unsigned int*)l, 16, 0, 0);
}

// ---------------- kernel 1: style modulation ----------------
__global__ void k_style(const float* __restrict__ style, const float* __restrict__ mod_w,
                        const float* __restrict__ mod_b, float* __restrict__ s_buf) {
    int b = blockIdx.x, c = threadIdx.x;
    const float* st = style + b * SD;
    const float* mw = mod_w + c * SD;
    float acc = 0.f;
    for (int d = 0; d < SD; ++d) acc += st[d] * mw[d];
    s_buf[b * CIN + c] = acc * MOD_SCALE_ + mod_b[c];
}

// ---------------- kernel 2: demodulated weights, bf16, o-major ----------------
// wgtT2[b][o][k], k = kk*CIN + c
__global__ void k_wgt(const float* __restrict__ weight, const float* __restrict__ s_buf,
                      unsigned short* __restrict__ wgtT2) {
    int o = blockIdx.x, b = blockIdx.y;
    int c = threadIdx.x;
    float s = s_buf[b * CIN + c];
    const float* wp = weight + (o * CIN + c) * KK_;
    float w[KK_];
    float p = 0.f;
#pragma unroll
    for (int i = 0; i < KK_; ++i) { w[i] = SCALE_ * wp[i] * s; p += w[i] * w[i]; }
    __shared__ float red[256];
    red[c] = p;
    __syncthreads();
    for (int s2 = 128; s2 > 0; s2 >>= 1) {
        if (c < s2) red[c] += red[c + s2];
        __syncthreads();
    }
    float demod = rsqrtf(red[0] + 1e-8f);
    unsigned short* dst = wgtT2 + ((size_t)(b * COUT + o)) * KTOT + c;
#pragma unroll
    for (int i = 0; i < KK_; ++i) dst[(size_t)i * CIN] = f2bf(w[i] * demod);
}

// ---------------- kernel 2b: input transpose -> in_t[b][y][x][c] bf16 ----------------
__global__ __launch_bounds__(256) void k_tr(const float* __restrict__ in,
                                            unsigned short* __restrict__ in_t) {
    const int y = blockIdx.x, cc = blockIdx.y, b = blockIdx.z;
    const int tid = threadIdx.x;
    __shared__ unsigned short t[64][65];
    for (int e = tid; e < 4096; e += 256) {
        int c = e >> 6, x = e & 63;
        t[c][x] = f2bf(in[((size_t)(b * CIN + cc * 64 + c)) * HW + y * W_ + x]);
    }
    __syncthreads();
    for (int e = tid; e < 2048; e += 256) {
        int x = e >> 5, cp = e & 31;
        int c = cp * 2;
        unsigned int lo = t[c][x], hi = t[c + 1][x];
        unsigned int v = lo | (hi << 16);
        unsigned int* dst = (unsigned int*)(in_t + ((size_t)(b * HW + y * W_ + x)) * CIN + cc * 64);
        dst[cp] = v;
    }
}

// ---------------- kernel 3: FUSED deformable-im2col + bf16 MFMA GEMM ----------------
// One block per (b, image row). Block tile 256(O) x 64(P), BK=64, 8 waves (wave 64x32).
// B-tile sampled on the fly from channel-last in_t (L2-resident); A via global_load_lds
// with inverse-source XOR swizzle; both double-buffered, 1 barrier per K-step.
__global__ __launch_bounds__(512) void k_gemm_fused(
    const unsigned short* __restrict__ in_t, const float* __restrict__ off,
    const float* __restrict__ msk, const unsigned short* __restrict__ wgtT2,
    const float* __restrict__ bias1, const float* __restrict__ bias2,
    float* __restrict__ mid) {
    // XCD-aware swizzle: 256 blocks -> each XCD gets 32 consecutive (b,y) ids
    const int bid = blockIdx.x;
    const int swz = (bid & 7) * 32 + (bid >> 3);
    const int b = swz >> 6;
    const int y = swz & 63;
    const int p0 = y * 64;

    const int tid = threadIdx.x;
    const int w  = tid >> 6, l = tid & 63;
    const int lo = l & 15, lg = l >> 4;
    const int wo = w >> 1, wp = w & 1;     // wave tile: 64 o x 32 p

    __shared__ float stw[KK_][4][64];                // 9 KB taps: weights
    __shared__ int   stix[KK_][4][64];               // 9 KB taps: indices (x CIN)
    __shared__ unsigned short a_lds[2][256 * 64];    // 64 KB A dbuf [o][k]
    __shared__ unsigned short b_lds[2][64 * 64];     // 16 KB B dbuf [p][k]

    // ---- taps: 9 kk x 64 px ----
    for (int e = tid; e < KK_ * 64; e += 512) {
        int kk = e >> 6, x = e & 63;
        float oy = off[(((size_t)b * 2 * KK_ + 2 * kk + 0) * H_ + y) * W_ + x];
        float ox = off[(((size_t)b * 2 * KK_ + 2 * kk + 1) * H_ + y) * W_ + x];
        float m  = msk[(((size_t)b * KK_ + kk) * H_ + y) * W_ + x];
        float py = (float)(y + kk / 3 - 1) + oy;
        float px = (float)(x + kk % 3 - 1) + ox;
        float y0f = floorf(py), x0f = floorf(px);
        float dy = py - y0f, dx = px - x0f;
        int y0 = (int)y0f, x0 = (int)x0f;
        int y1 = y0 + 1, x1 = x0 + 1;
        bool vy0 = (y0 >= 0) & (y0 < H_), vy1 = (y1 >= 0) & (y1 < H_);
        bool vx0 = (x0 >= 0) & (x0 < W_), vx1 = (x1 >= 0) & (x1 < W_);
        int cy0 = min(max(y0, 0), H_ - 1), cy1 = min(max(y1, 0), H_ - 1);
        int cx0 = min(max(x0, 0), W_ - 1), cx1 = min(max(x1, 0), W_ - 1);
        float wy0 = 1.f - dy, wy1 = dy, wx0 = 1.f - dx, wx1 = dx;
        stw[kk][0][x] = (vy0 && vx0) ? m * wy0 * wx0 : 0.f;  stix[kk][0][x] = (cy0 * W_ + cx0) * CIN;
        stw[kk][1][x] = (vy0 && vx1) ? m * wy0 * wx1 : 0.f;  stix[kk][1][x] = (cy0 * W_ + cx1) * CIN;
        stw[kk][2][x] = (vy1 && vx0) ? m * wy1 * wx0 : 0.f;  stix[kk][2][x] = (cy1 * W_ + cx0) * CIN;
        stw[kk][3][x] = (vy1 && vx1) ? m * wy1 * wx1 : 0.f;  stix[kk][3][x] = (cy1 * W_ + cx1) * CIN;
    }
    __syncthreads();

    const unsigned short* Abase = wgtT2 + (size_t)b * COUT * KTOT;
    const unsigned short* Ibase = in_t + (size_t)b * HW * CIN;

    // staging geometry
    const int arow  = tid >> 3;                        // 0..63 (+64*i)
    const int asoff = (((tid & 7) ^ (arow & 7)) * 8);  // swizzled 16B slot (ushorts)
    const int bp    = tid >> 3;                        // pixel 0..63
    const int bcg   = tid & 7;                         // channel-group (8 ch)
    const int bslot = ((bcg ^ (bp & 7)) * 8);

    f32x4 acc[4][2] = {};

    // ---- prologue: stage tile 0 ----
    {
        // B tile 0: kk=0, c0=0
        float gw0 = stw[0][0][bp], gw1 = stw[0][1][bp], gw2 = stw[0][2][bp], gw3 = stw[0][3][bp];
        const unsigned short* gp = Ibase + bcg * 8;
        bf16x8 g0 = *(const bf16x8*)(gp + stix[0][0][bp]);
        bf16x8 g1 = *(const bf16x8*)(gp + stix[0][1][bp]);
        bf16x8 g2 = *(const bf16x8*)(gp + stix[0][2][bp]);
        bf16x8 g3 = *(const bf16x8*)(gp + stix[0][3][bp]);
#pragma unroll
        for (int i = 0; i < 4; ++i)
            gload_lds16(Abase + (size_t)(arow + i * 64) * KTOT + asoff,
                        &a_lds[0][(size_t)(tid + i * 512) * 8]);
        bf16x8 r;
#pragma unroll
        for (int j = 0; j < 8; ++j)
            r[j] = (__bf16)(gw0 * (float)g0[j] + gw1 * (float)g1[j]
                          + gw2 * (float)g2[j] + gw3 * (float)g3[j]);
        *(bf16x8*)&b_lds[0][bp * 64 + bslot] = r;
    }
    __syncthreads();

    for (int t = 0; t < 36; ++t) {
        const int cur = t & 1, nxt = cur ^ 1;
        bf16x8 g0, g1, g2, g3;
        float gw0, gw1, gw2, gw3;
        if (t < 35) {
            const int kk1 = (t + 1) >> 2, c01 = ((t + 1) & 3) << 6;
            gw0 = stw[kk1][0][bp]; gw1 = stw[kk1][1][bp];
            gw2 = stw[kk1][2][bp]; gw3 = stw[kk1][3][bp];
            const unsigned short* gp = Ibase + c01 + bcg * 8;
            g0 = *(const bf16x8*)(gp + stix[kk1][0][bp]);
            g1 = *(const bf16x8*)(gp + stix[kk1][1][bp]);
            g2 = *(const bf16x8*)(gp + stix[kk1][2][bp]);
            g3 = *(const bf16x8*)(gp + stix[kk1][3][bp]);
#pragma unroll
            for (int i = 0; i < 4; ++i)
                gload_lds16(Abase + (size_t)(arow + i * 64) * KTOT + (t + 1) * 64 + asoff,
                            &a_lds[nxt][(size_t)(tid + i * 512) * 8]);
        }

        bf16x8 af[4][2], bfr[2][2];
#pragma unroll
        for (int mi = 0; mi < 4; ++mi) {
            int R = wo * 64 + mi * 16 + lo;
#pragma unroll
            for (int kki = 0; kki < 2; ++kki)
                af[mi][kki] = *(const bf16x8*)&a_lds[cur][R * 64 + (((kki * 4 + lg) ^ (R & 7)) * 8)];
        }
#pragma unroll
        for (int ni = 0; ni < 2; ++ni) {
            int P = wp * 32 + ni * 16 + lo;
#pragma unroll
            for (int kki = 0; kki < 2; ++kki)
                bfr[ni][kki] = *(const bf16x8*)&b_lds[cur][P * 64 + (((kki * 4 + lg) ^ (P & 7)) * 8)];
        }
#pragma unroll
        for (int kki = 0; kki < 2; ++kki)
#pragma unroll
            for (int mi = 0; mi < 4; ++mi)
#pragma unroll
                for (int ni = 0; ni < 2; ++ni)
                    acc[mi][ni] = __builtin_amdgcn_mfma_f32_16x16x32_bf16(
                        af[mi][kki], bfr[ni][kki], acc[mi][ni], 0, 0, 0);

        if (t < 35) {
            bf16x8 r;
#pragma unroll
            for (int j = 0; j < 8; ++j)
                r[j] = (__bf16)(gw0 * (float)g0[j] + gw1 * (float)g1[j]
                              + gw2 * (float)g2[j] + gw3 * (float)g3[j]);
            *(bf16x8*)&b_lds[nxt][bp * 64 + bslot] = r;
            __syncthreads();
        }
    }

    // ---- epilogue: bias1 -> lrelu -> *sqrt2 -> bias2 -> lrelu -> *sqrt2 ----
    float* mb = mid + ((size_t)b * COUT) * HW;
#pragma unroll
    for (int mi = 0; mi < 4; ++mi) {
        int obase = wo * 64 + mi * 16 + lg * 4;
#pragma unroll
        for (int ni = 0; ni < 2; ++ni) {
            int p = p0 + wp * 32 + ni * 16 + lo;
#pragma unroll
            for (int r = 0; r < 4; ++r) {
                int oo = obase + r;
                float v = acc[mi][ni][r] + bias1[oo];
                v = (v > 0.f ? v : 0.2f * v) * SQRT2_;
                v += bias2[oo];
                v = (v > 0.f ? v : 0.2f * v) * SQRT2_;
                mb[(size_t)oo * HW + p] = v;
            }
        }
    }
}

// ---------------- kernel 4: separable x2-upsample FIR blur ----------------
__global__ __launch_bounds__(256) void k_blur(const float* __restrict__ mid,
                                              float* __restrict__ out) {
    const int bo = blockIdx.x;
    const int tid = threadIdx.x;
    __shared__ float m[64][64];
    __shared__ float vt[128][65];

    const float4* src = (const float4*)(mid + (size_t)bo * HW);
#pragma unroll
    for (int i = 0; i < 4; ++i)
        ((float4*)m)[tid + 256 * i] = src[tid + 256 * i];
    __syncthreads();

#pragma unroll
    for (int i = 0; i < 32; ++i) {
        int e = tid + 256 * i;
        int Y = e >> 6, x = e & 63;
        int h = Y >> 1;
        float acc;
        if (Y & 1) acc = 3.f * m[h][x] + ((h + 1 < 64) ? m[h + 1][x] : 0.f);
        else       acc = ((h >= 1) ? m[h - 1][x] : 0.f) + 3.f * m[h][x];
        vt[Y][x] = acc;
    }
    __syncthreads();

    float4* dst = (float4*)(out + (size_t)bo * 128 * 128);
#pragma unroll
    for (int i = 0; i < 16; ++i) {
        int e = tid + 256 * i;
        int Y = e >> 5, t = e & 31;
        const float* v = vt[Y];
        int c = 2 * t;
        float vm1 = (c >= 1) ? v[c - 1] : 0.f;
        float v0 = v[c];
        float v1 = v[c + 1];
        float vp2 = (c + 2 < 64) ? v[c + 2] : 0.f;
        float4 r;
        r.x = (vm1 + 3.f * v0) * (1.f / 16.f);
        r.y = (3.f * v0 + v1)  * (1.f / 16.f);
        r.z = (v0 + 3.f * v1)  * (1.f / 16.f);
        r.w = (3.f * v1 + vp2) * (1.f / 16.f);
        dst[e] = r;
    }
}

// ---------------- launch ----------------
extern "C" void kernel_launch(void* const* d_in, const int* in_sizes, int n_in,
                              void* d_out, int out_size, void* d_ws, size_t ws_size,
                              hipStream_t stream) {
    const float* input  = (const float*)d_in[0];
    const float* style  = (const float*)d_in[1];
    const float* offset = (const float*)d_in[2];
    const float* mask   = (const float*)d_in[3];
    const float* weight = (const float*)d_in[4];
    const float* mod_w  = (const float*)d_in[5];
    const float* mod_b  = (const float*)d_in[6];
    const float* bias1  = (const float*)d_in[7];
    const float* bias2  = (const float*)d_in[8];
    float* out = (float*)d_out;

    // ws layout (bytes): s_buf 4K | wgtT2 bf16 4.72M | in_t bf16 8.39M | mid f32 16.78M
    char* ws = (char*)d_ws;
    float*          s_buf = (float*)ws;
    unsigned short* wgtT2 = (unsigned short*)(ws + 4096);
    unsigned short* in_t  = (unsigned short*)(ws + 4096 + (size_t)B_ * COUT * KTOT * 2);
    float*          mid   = (float*)(ws + 4096 + (size_t)B_ * COUT * KTOT * 2
                                               + (size_t)B_ * HW * CIN * 2);

    k_style <<<dim3(B_), dim3(256), 0, stream>>>(style, mod_w, mod_b, s_buf);
    k_wgt   <<<dim3(COUT, B_), dim3(256), 0, stream>>>(weight, s_buf, wgtT2);
    k_tr    <<<dim3(H_, CIN / 64, B_), dim3(256), 0, stream>>>(input, in_t);
    k_gemm_fused<<<dim3(B_ * H_), dim3(512), 0, stream>>>(in_t, offset, mask, wgtT2,
                                                          bias1, bias2, mid);
    k_blur  <<<dim3(B_ * COUT), dim3(256), 0, stream>>>(mid, out);
}